// Round 9
// baseline (4803.497 us; speedup 1.0000x reference)
//
#include <hip/hip_runtime.h>
#include <hip/hip_bf16.h>

#define B_ 2
#define H_ 4
#define T_ 2048
#define NH_ 8192
#define D_ 256

typedef __attribute__((ext_vector_type(4))) float f32x4;
typedef __attribute__((ext_vector_type(8))) short bf16x8;
typedef __attribute__((ext_vector_type(4))) int i32x4;

__device__ __forceinline__ unsigned short f2bf(float f) {
    union { float f; unsigned u; } v;
    v.f = f;
    unsigned u = v.u;
    unsigned r = u + 0x7FFFu + ((u >> 16) & 1u);   // RNE
    return (unsigned short)(r >> 16);
}

// ---------------------------------------------------------------------------
// Kernel 1: RoPE + cast to bf16 for Q and K  (HBM-bound, ~77% of achievable)
// ---------------------------------------------------------------------------
__global__ __launch_bounds__(256) void rope_cast_kernel(
    const float* __restrict__ Q, const float* __restrict__ K,
    unsigned short* __restrict__ Qb, unsigned short* __restrict__ Kb,
    int bh0)
{
    const long gid = (long)blockIdx.x * 256 + threadIdx.x;  // one 8-elem group
    const int ng = NH_ / 8;
    const int n8 = (int)(gid % ng) * 8;
    const long row = gid / ng;              // lbh*T + t
    const int t = (int)(row % T_);
    const int lbh = (int)(row / T_);

    const long in_off  = ((long)(bh0 + lbh) * T_ + t) * NH_ + n8;
    const long out_off = ((long)lbh * T_ + t) * NH_ + n8;

    float4 qa = *(const float4*)(Q + in_off);
    float4 qb4 = *(const float4*)(Q + in_off + 4);
    float4 ka = *(const float4*)(K + in_off);
    float4 kb4 = *(const float4*)(K + in_off + 4);
    float qv[8] = {qa.x, qa.y, qa.z, qa.w, qb4.x, qb4.y, qb4.z, qb4.w};
    float kv[8] = {ka.x, ka.y, ka.z, ka.w, kb4.x, kb4.y, kb4.z, kb4.w};

    union { i32x4 v; unsigned short u[8]; } qo, ko;
    const int p0 = n8 >> 1;
    const float tf = (float)t;
#pragma unroll
    for (int j = 0; j < 4; ++j) {
        float freq = exp2f(-(float)(p0 + j) * (1.0f / 256.0f)) * 0.15915494309189535f;
        float phase = tf * freq;
        float r = phase - floorf(phase);
        float ph = r * 6.283185307179586f;
        float c = __cosf(ph);
        float s = __sinf(ph);
        float qe = qv[2 * j], qodd = qv[2 * j + 1];
        float ke = kv[2 * j], kodd = kv[2 * j + 1];
        qo.u[2 * j]     = f2bf(qe * c - qodd * s);
        qo.u[2 * j + 1] = f2bf(qodd * c + qe * s);
        ko.u[2 * j]     = f2bf(ke * c - kodd * s);
        ko.u[2 * j + 1] = f2bf(kodd * c + ke * s);
    }
    *(i32x4*)(Qb + out_off) = qo.v;
    *(i32x4*)(Kb + out_off) = ko.v;
}

// ---------------------------------------------------------------------------
// Kernel 2: V [B,T,D] fp32 -> Vt [B,D,T] bf16 (transposed cast, LDS tiled)
// ---------------------------------------------------------------------------
__global__ __launch_bounds__(256) void vcast_kernel(
    const float* __restrict__ V, unsigned short* __restrict__ Vt)
{
    __shared__ unsigned short tile[64][72];
    const int t0 = blockIdx.x * 64;
    const int d0 = blockIdx.y * 64;
    const int b = blockIdx.z;
    const int tid = threadIdx.x;
#pragma unroll
    for (int rr = 0; rr < 16; ++rr) {
        int tl = rr * 4 + (tid >> 6);
        int dl = tid & 63;
        float v = V[((long)b * T_ + (t0 + tl)) * D_ + d0 + dl];
        tile[dl][tl] = f2bf(v);
    }
    __syncthreads();
#pragma unroll
    for (int rr = 0; rr < 16; ++rr) {
        int dl = rr * 4 + (tid >> 6);
        int tl = tid & 63;
        Vt[((long)b * D_ + (d0 + dl)) * T_ + t0 + tl] = tile[dl][tl];
    }
}

// ---------------------------------------------------------------------------
// gemm1: S = mask(Qr . Kr^T).  WIDE TILE BM=256 x BN=512 (A-panel staged once
// serves 512 output cols: panel traffic 2.42 -> 2.01 GB at the confirmed
// ~8 TB/s fabric ceiling).  1024 threads / 16 waves (2x8), wave-tile 128x64
// (same per-wave structure as R8), BK=32, triple-buffered 144 KiB LDS,
// counted vmcnt(3), both-sides XOR swizzle (0-conflict verified), setprio.
// 160 jobs (20/bh), single round.  Masked diagonal waste ~11% MFMA (slack).
// ---------------------------------------------------------------------------
#define GLD16(g, l) __builtin_amdgcn_global_load_lds(                         \
    (const __attribute__((address_space(1))) void*)(g),                       \
    (__attribute__((address_space(3))) void*)(l), 16, 0, 0)

__global__ __launch_bounds__(1024, 1) void gemm1_kernel(
    const unsigned short* __restrict__ Qb, const unsigned short* __restrict__ Kb,
    unsigned short* __restrict__ S, int nwg)
{
    __shared__ __align__(16) unsigned short As[3][256][32];   // 48 KiB
    __shared__ __align__(16) unsigned short Bs[3][512][32];   // 96 KiB

    // bijective XCD swizzle (m204 variant, any nwg)
    const int orig = blockIdx.x;
    const int xcd = orig & 7, q8 = nwg >> 3, r8 = nwg & 7;
    const int wg = (xcd < r8 ? xcd * (q8 + 1) : r8 * (q8 + 1) + (xcd - r8) * q8)
                 + (orig >> 3);

    // job decode: per bh, (it, j2) with j2 <= it/2; 20 jobs/bh
    const int t20 = wg % 20;
    const int lbh = wg / 20;
    int it = 0, rem = t20;
    while (rem >= (it >> 1) + 1) { rem -= (it >> 1) + 1; ++it; }
    const int j2 = rem;

    const int tid = threadIdx.x;
    const int lane = tid & 63;
    const int wid = tid >> 6;                // 0..15
    const int wr = wid >> 3;                 // 0..1 (128-row half)
    const int wc = wid & 7;                  // 0..7 (64-col slice)
    const int rofs = lane & 15;
    const int sl8 = (((lane >> 4) ^ ((lane >> 1) & 3))) << 3;  // read swizzle

    // staging: 1024 threads, 3 GLD16 each per K-tile (A 16KB + B 32KB)
    const int ss8 = (((tid & 3) ^ ((tid >> 3) & 3))) << 3;     // src pre-swizzle
    const int dst = tid * 8;                 // elems within one [256][32] chunk
    const unsigned short* Ab = Qb + (long)lbh * T_ * NH_ + (long)it * 256 * NH_;
    const unsigned short* Bb = Kb + (long)lbh * T_ * NH_ + (long)j2 * 512 * NH_;
    const unsigned short* gA0 = Ab + (long)(tid >> 2) * NH_ + ss8;
    const unsigned short* gB0 = Bb + (long)(tid >> 2) * NH_ + ss8;
    const unsigned short* gB1 = gB0 + 256L * NH_;
    unsigned short* AsB = &As[0][0][0];
    unsigned short* BsB = &Bs[0][0][0];

    f32x4 acc[8][4];
#pragma unroll
    for (int m = 0; m < 8; ++m)
#pragma unroll
        for (int n = 0; n < 4; ++n)
            acc[m][n] = (f32x4){0.f, 0.f, 0.f, 0.f};

#define GW_STAGE(SB, kt) {                                                    \
    const long ko_ = (long)(kt) * 32;                                         \
    GLD16(gA0 + ko_, AsB + (SB) * 8192 + dst);                                \
    GLD16(gB0 + ko_, BsB + (SB) * 16384 + dst);                               \
    GLD16(gB1 + ko_, BsB + (SB) * 16384 + 8192 + dst); }

    // prologue: tiles 0,1 in flight (6 loads); wait for tile 0 only
    GW_STAGE(0, 0)
    GW_STAGE(1, 1)
    asm volatile("s_waitcnt vmcnt(3)" ::: "memory");
    __builtin_amdgcn_s_barrier();
    __builtin_amdgcn_sched_barrier(0);

    const int arow = wr * 128 + rofs;
    const int brow = wc * 64 + rofs;
#pragma unroll 1
    for (int t = 0; t < 256; ++t) {
        const int rb = t % 3;
        bf16x8 af[8], bv[4];
        const unsigned short* ab = AsB + rb * 8192 + sl8;
        const unsigned short* bb = BsB + rb * 16384 + sl8;
#pragma unroll
        for (int n = 0; n < 4; ++n)
            bv[n] = *(const bf16x8*)(bb + (brow + n * 16) * 32);
#pragma unroll
        for (int m = 0; m < 8; ++m)
            af[m] = *(const bf16x8*)(ab + (arow + m * 16) * 32);
        if (t + 2 < 256) { const int sb = (t + 2) % 3; GW_STAGE(sb, t + 2) }
        __builtin_amdgcn_s_setprio(1);
#pragma unroll
        for (int m = 0; m < 8; ++m)
#pragma unroll
            for (int n = 0; n < 4; ++n)
                acc[m][n] = __builtin_amdgcn_mfma_f32_16x16x32_bf16(
                    af[m], bv[n], acc[m][n], 0, 0, 0);
        __builtin_amdgcn_s_setprio(0);
        if (t < 254) {
            asm volatile("s_waitcnt vmcnt(3)" ::: "memory");
            __builtin_amdgcn_s_barrier();
            __builtin_amdgcn_sched_barrier(0);
        } else if (t == 254) {
            asm volatile("s_waitcnt vmcnt(0)" ::: "memory");
            __builtin_amdgcn_s_barrier();
            __builtin_amdgcn_sched_barrier(0);
        }
    }

    // epilogue: strict-lower mask, bf16 store
    unsigned short* Sp = S + (long)lbh * T_ * T_;
    const int r0 = it * 256 + wr * 128 + ((lane >> 4) << 2);
    const int c0 = j2 * 512 + wc * 64 + (lane & 15);
#pragma unroll
    for (int m = 0; m < 8; ++m) {
#pragma unroll
        for (int i = 0; i < 4; ++i) {
            const int rr = r0 + m * 16 + i;
#pragma unroll
            for (int n = 0; n < 4; ++n) {
                const int cc = c0 + n * 16;
                float v = (cc < rr) ? acc[m][n][i] : 0.0f;
                Sp[(long)rr * T_ + cc] = f2bf(v);
            }
        }
    }
#undef GW_STAGE
}

// ---------------------------------------------------------------------------
// gemm2 (m97 structure, 128x128): O = S . V
// ---------------------------------------------------------------------------
__device__ __forceinline__ void stage_tile(const unsigned short* g, long ldk,
                                           unsigned short* l, int tid)
{
    const int row = tid >> 2;
    const int col = (tid & 3) << 3;
    const unsigned short* g0 = g + (long)row * ldk + col;
    const unsigned short* g1 = g0 + 64 * ldk;
    unsigned short* l0 = l + tid * 8;
    unsigned short* l1 = l0 + 2048;
    GLD16(g0, l0);
    GLD16(g1, l1);
}

__global__ __launch_bounds__(256) void gemm2_kernel(
    const unsigned short* __restrict__ S, const unsigned short* __restrict__ Vt,
    float* __restrict__ Out, int bh0)
{
    const int jn = blockIdx.x;
    const int it = blockIdx.y;
    const int lbh = blockIdx.z;
    const int bh = bh0 + lbh;
    const int b = bh / H_;

    __shared__ __align__(16) unsigned short As2[2][128][32];
    __shared__ __align__(16) unsigned short Bs2[2][128][32];

    const unsigned short* A  = S + (long)lbh * T_ * T_ + (long)it * 128 * T_;
    const unsigned short* Bm = Vt + (long)b * D_ * T_ + (long)jn * 128 * T_;
    const int KT = (it + 1) * 4;

    const int tid = threadIdx.x;
    const int lane = tid & 63;
    const int wid = tid >> 6;
    const int wr = wid >> 1;
    const int wc = wid & 1;
    f32x4 acc[4][4];
#pragma unroll
    for (int m = 0; m < 4; ++m)
#pragma unroll
        for (int n = 0; n < 4; ++n)
            acc[m][n] = (f32x4){0.f, 0.f, 0.f, 0.f};
    const int rofs = lane & 15;
    const int kofs = (lane >> 4) * 8;
    stage_tile(A, T_, &As2[0][0][0], tid);
    stage_tile(Bm, T_, &Bs2[0][0][0], tid);
    int cur = 0;
    for (int kt = 0; kt < KT; ++kt) {
        __syncthreads();
        if (kt + 1 < KT) {
            stage_tile(A + (long)(kt + 1) * 32, T_, &As2[cur ^ 1][0][0], tid);
            stage_tile(Bm + (long)(kt + 1) * 32, T_, &Bs2[cur ^ 1][0][0], tid);
        }
        bf16x8 af[4], bfr[4];
#pragma unroll
        for (int m = 0; m < 4; ++m)
            af[m] = *(const bf16x8*)&As2[cur][wr * 64 + m * 16 + rofs][kofs];
#pragma unroll
        for (int n = 0; n < 4; ++n)
            bfr[n] = *(const bf16x8*)&Bs2[cur][wc * 64 + n * 16 + rofs][kofs];
#pragma unroll
        for (int m = 0; m < 4; ++m)
#pragma unroll
            for (int n = 0; n < 4; ++n)
                acc[m][n] = __builtin_amdgcn_mfma_f32_16x16x32_bf16(
                    af[m], bfr[n], acc[m][n], 0, 0, 0);
        cur ^= 1;
    }

    float* Op = Out + ((long)bh * T_ + it * 128) * D_ + jn * 128;
#pragma unroll
    for (int m = 0; m < 4; ++m) {
        const int rbase = wr * 64 + m * 16 + ((lane >> 4) << 2);
#pragma unroll
        for (int i = 0; i < 4; ++i) {
            const int rr = rbase + i;
#pragma unroll
            for (int n = 0; n < 4; ++n) {
                const int cc = wc * 64 + n * 16 + (lane & 15);
                Op[(long)rr * D_ + cc] = acc[m][n][i];
            }
        }
    }
}

// ---------------------------------------------------------------------------
extern "C" void kernel_launch(void* const* d_in, const int* in_sizes, int n_in,
                              void* d_out, int out_size, void* d_ws, size_t ws_size,
                              hipStream_t stream)
{
    const float* Q = (const float*)d_in[0];
    const float* K = (const float*)d_in[1];
    const float* V = (const float*)d_in[2];
    float* Out = (float*)d_out;

    const size_t vt_elems = (size_t)B_ * D_ * T_;                 // bf16
    auto need = [&](int c) {
        return 2 * vt_elems + (size_t)c * T_ * NH_ * 2 * 2        // Qb+Kb bytes
             + (size_t)c * T_ * T_ * 2;                           // S bytes
    };
    int c;
    if      (ws_size >= need(8)) c = 8;
    else if (ws_size >= need(4)) c = 4;
    else if (ws_size >= need(2)) c = 2;
    else if (ws_size >= need(1)) c = 1;
    else return;

    unsigned short* Vt = (unsigned short*)d_ws;
    unsigned short* Qb = Vt + vt_elems;
    unsigned short* Kb = Qb + (size_t)c * T_ * NH_;
    unsigned short* Sb = Kb + (size_t)c * T_ * NH_;

    vcast_kernel<<<dim3(T_ / 64, D_ / 64, B_), 256, 0, stream>>>(V, Vt);

    for (int bh0 = 0; bh0 < B_ * H_; bh0 += c) {
        const long groups = (long)c * T_ * (NH_ / 8);
        rope_cast_kernel<<<(int)(groups / 256), 256, 0, stream>>>(Q, K, Qb, Kb, bh0);
        const int nwg = 20 * c;
        gemm1_kernel<<<dim3(nwg), 1024, 0, stream>>>(Qb, Kb, Sb, nwg);
        gemm2_kernel<<<dim3(2, 16, c), 256, 0, stream>>>(Sb, Vt, Out, bh0);
    }
}

// Round 10
// 667.769 us; speedup vs baseline: 7.1934x; 7.1934x over previous
//
#include <hip/hip_runtime.h>
#include <hip/hip_bf16.h>

#define B_ 2
#define H_ 4
#define T_ 2048
#define NH_ 8192
#define D_ 256

typedef __attribute__((ext_vector_type(4))) float f32x4;
typedef __attribute__((ext_vector_type(8))) short bf16x8;
typedef __attribute__((ext_vector_type(4))) int i32x4;

__device__ __forceinline__ unsigned short f2bf(float f) {
    union { float f; unsigned u; } v;
    v.f = f;
    unsigned u = v.u;
    unsigned r = u + 0x7FFFu + ((u >> 16) & 1u);   // RNE
    return (unsigned short)(r >> 16);
}

// ---------------------------------------------------------------------------
// Kernel 1: RoPE + cast to bf16 for Q and K (HBM-bound).  v_cos/v_sin take
// REVOLUTIONS on gfx950 -> feed fract(phase) directly, skip __cosf's
// internal /2pi + fract re-reduction.
// ---------------------------------------------------------------------------
__global__ __launch_bounds__(256) void rope_cast_kernel(
    const float* __restrict__ Q, const float* __restrict__ K,
    unsigned short* __restrict__ Qb, unsigned short* __restrict__ Kb,
    int bh0)
{
    const long gid = (long)blockIdx.x * 256 + threadIdx.x;  // one 8-elem group
    const int ng = NH_ / 8;
    const int n8 = (int)(gid % ng) * 8;
    const long row = gid / ng;              // lbh*T + t
    const int t = (int)(row % T_);
    const int lbh = (int)(row / T_);

    const long in_off  = ((long)(bh0 + lbh) * T_ + t) * NH_ + n8;
    const long out_off = ((long)lbh * T_ + t) * NH_ + n8;

    float4 qa = *(const float4*)(Q + in_off);
    float4 qb4 = *(const float4*)(Q + in_off + 4);
    float4 ka = *(const float4*)(K + in_off);
    float4 kb4 = *(const float4*)(K + in_off + 4);
    float qv[8] = {qa.x, qa.y, qa.z, qa.w, qb4.x, qb4.y, qb4.z, qb4.w};
    float kv[8] = {ka.x, ka.y, ka.z, ka.w, kb4.x, kb4.y, kb4.z, kb4.w};

    union { i32x4 v; unsigned short u[8]; } qo, ko;
    const int p0 = n8 >> 1;
    const float tf = (float)t;
#pragma unroll
    for (int j = 0; j < 4; ++j) {
        float freq = exp2f(-(float)(p0 + j) * (1.0f / 256.0f)) * 0.15915494309189535f;
        float phase = tf * freq;
        float r = phase - floorf(phase);        // revolutions in [0,1)
        float c, s;
        asm("v_cos_f32 %0, %1" : "=v"(c) : "v"(r));
        asm("v_sin_f32 %0, %1" : "=v"(s) : "v"(r));
        float qe = qv[2 * j], qodd = qv[2 * j + 1];
        float ke = kv[2 * j], kodd = kv[2 * j + 1];
        qo.u[2 * j]     = f2bf(qe * c - qodd * s);
        qo.u[2 * j + 1] = f2bf(qodd * c + qe * s);
        ko.u[2 * j]     = f2bf(ke * c - kodd * s);
        ko.u[2 * j + 1] = f2bf(kodd * c + ke * s);
    }
    *(i32x4*)(Qb + out_off) = qo.v;
    *(i32x4*)(Kb + out_off) = ko.v;
}

// ---------------------------------------------------------------------------
// Kernel 2: V [B,T,D] fp32 -> Vt [B,D,T] bf16 (transposed cast, LDS tiled)
// ---------------------------------------------------------------------------
__global__ __launch_bounds__(256) void vcast_kernel(
    const float* __restrict__ V, unsigned short* __restrict__ Vt)
{
    __shared__ unsigned short tile[64][72];
    const int t0 = blockIdx.x * 64;
    const int d0 = blockIdx.y * 64;
    const int b = blockIdx.z;
    const int tid = threadIdx.x;
#pragma unroll
    for (int rr = 0; rr < 16; ++rr) {
        int tl = rr * 4 + (tid >> 6);
        int dl = tid & 63;
        float v = V[((long)b * T_ + (t0 + tl)) * D_ + d0 + dl];
        tile[dl][tl] = f2bf(v);
    }
    __syncthreads();
#pragma unroll
    for (int rr = 0; rr < 16; ++rr) {
        int dl = rr * 4 + (tid >> 6);
        int tl = tid & 63;
        Vt[((long)b * D_ + (d0 + dl)) * T_ + t0 + tl] = tile[dl][tl];
    }
}

// ---------------------------------------------------------------------------
// gemm1: S = mask(Qr . Kr^T).  EXACT R8 core (256x256, 512 thr / 8 waves,
// 96 KiB triple-buffer, vmcnt(4), both-sides swizzle, setprio; VGPR ~100 --
// R9's 1024-thr variant spilled acc to scratch: 15.7 GB traffic, NEVER again).
// NEW: XCD-LOCAL schedule.  lbh = blockIdx&7 pins each bh's triangle to one
// XCD (blockIdx%8 round-robin): 32 co-resident full tiles share 8 A-slices +
// 8 B-slices per K-step (256 KB L2 window) -> panels pulled from L3 once per
// XCD (~0.7 GB total vs 2.42 GB).  Packing: last 4 tiles of EACH lbh split
// into 8 K-chunks (f32 partials + reduce, proven R8) -> per XCD 32 full + 32
// chunk jobs = 1 full + ~1/8 per CU.
// ---------------------------------------------------------------------------
#define GLD16(g, l) __builtin_amdgcn_global_load_lds(                         \
    (const __attribute__((address_space(1))) void*)(g),                       \
    (__attribute__((address_space(3))) void*)(l), 16, 0, 0)

__global__ __launch_bounds__(512, 2) void gemm1_kernel(
    const unsigned short* __restrict__ Qb, const unsigned short* __restrict__ Kb,
    unsigned short* __restrict__ S, float* __restrict__ part, int split)
{
    __shared__ __align__(16) unsigned short As[3][256][32];   // 48 KiB
    __shared__ __align__(16) unsigned short Bs[3][256][32];   // 48 KiB

    const int bidx = blockIdx.x;
    int lbh, t36, KT, kc, pidx;
    bool full;
    if (split) {
        // grid 512: xcd-local decode, c==8
        lbh = bidx & 7;
        const int s = bidx >> 3;             // 0..63
        if (s < 32) { t36 = s; KT = 256; kc = 0; full = true; pidx = 0; }
        else {
            const int j = s - 32;            // 0..31
            t36 = 32 + (j >> 3);             // 32..35
            kc = j & 7;
            KT = 32; full = false;
            pidx = (lbh * 4 + (t36 - 32)) * 8 + kc;
        }
    } else {
        lbh = bidx / 36; t36 = bidx % 36; KT = 256; kc = 0; full = true; pidx = 0;
    }
    int it = (int)((sqrtf(8.0f * (float)t36 + 1.0f) - 1.0f) * 0.5f);
    if ((it + 1) * (it + 2) / 2 <= t36) ++it;
    if (it * (it + 1) / 2 > t36) --it;
    const int jt = t36 - it * (it + 1) / 2;

    const int tid = threadIdx.x;
    const int lane = tid & 63;
    const int wid = tid >> 6;                // 0..7
    const int wr = wid >> 2;                 // 0..1 (128-row half)
    const int wc = wid & 3;                  // 0..3 (64-col quarter)
    const int rofs = lane & 15;
    const int sl8 = (((lane >> 4) ^ ((lane >> 1) & 3))) << 3;  // read swizzle

    // staging: 512 threads, 4 GLD16 each per K-tile (A 16KB + B 16KB)
    const int ss8 = (((tid & 3) ^ ((tid >> 3) & 3))) << 3;     // src pre-swizzle
    const int dst = tid * 8;                 // elems within one [128][32] half
    const long K0 = (long)kc * 1024;
    const unsigned short* Ab = Qb + (long)lbh * T_ * NH_ + (long)it * 256 * NH_ + K0;
    const unsigned short* Bb = Kb + (long)lbh * T_ * NH_ + (long)jt * 256 * NH_ + K0;
    const unsigned short* gA0 = Ab + (long)(tid >> 2) * NH_ + ss8;
    const unsigned short* gA1 = gA0 + 128L * NH_;
    const unsigned short* gB0 = Bb + (long)(tid >> 2) * NH_ + ss8;
    const unsigned short* gB1 = gB0 + 128L * NH_;
    unsigned short* AsB = &As[0][0][0];
    unsigned short* BsB = &Bs[0][0][0];

    f32x4 acc[8][4];
#pragma unroll
    for (int m = 0; m < 8; ++m)
#pragma unroll
        for (int n = 0; n < 4; ++n)
            acc[m][n] = (f32x4){0.f, 0.f, 0.f, 0.f};

#define G256_STAGE(SB, kt) {                                                  \
    const long ko_ = (long)(kt) * 32;                                         \
    GLD16(gA0 + ko_, AsB + (SB) * 8192 + dst);                                \
    GLD16(gA1 + ko_, AsB + (SB) * 8192 + 4096 + dst);                         \
    GLD16(gB0 + ko_, BsB + (SB) * 8192 + dst);                                \
    GLD16(gB1 + ko_, BsB + (SB) * 8192 + 4096 + dst); }

    // prologue: tiles 0,1 in flight (8 loads); wait for tile 0 only
    G256_STAGE(0, 0)
    G256_STAGE(1, 1)
    asm volatile("s_waitcnt vmcnt(4)" ::: "memory");
    __builtin_amdgcn_s_barrier();
    __builtin_amdgcn_sched_barrier(0);

    const int arow = wr * 128 + rofs;
    const int brow = wc * 64 + rofs;
#pragma unroll 1
    for (int t = 0; t < KT; ++t) {
        const int rb = t % 3;
        bf16x8 af[8], bv[4];
        const unsigned short* ab = AsB + rb * 8192 + sl8;
        const unsigned short* bb = BsB + rb * 8192 + sl8;
#pragma unroll
        for (int n = 0; n < 4; ++n)
            bv[n] = *(const bf16x8*)(bb + (brow + n * 16) * 32);
#pragma unroll
        for (int m = 0; m < 8; ++m)
            af[m] = *(const bf16x8*)(ab + (arow + m * 16) * 32);
        if (t + 2 < KT) { const int sb = (t + 2) % 3; G256_STAGE(sb, t + 2) }
        __builtin_amdgcn_s_setprio(1);
#pragma unroll
        for (int m = 0; m < 8; ++m)
#pragma unroll
            for (int n = 0; n < 4; ++n)
                acc[m][n] = __builtin_amdgcn_mfma_f32_16x16x32_bf16(
                    af[m], bv[n], acc[m][n], 0, 0, 0);
        __builtin_amdgcn_s_setprio(0);
        if (t < KT - 2) {
            asm volatile("s_waitcnt vmcnt(4)" ::: "memory");
            __builtin_amdgcn_s_barrier();
            __builtin_amdgcn_sched_barrier(0);
        } else if (t == KT - 2) {
            asm volatile("s_waitcnt vmcnt(0)" ::: "memory");
            __builtin_amdgcn_s_barrier();
            __builtin_amdgcn_sched_barrier(0);
        }
    }

    if (full) {
        // strict-lower mask, bf16 store
        unsigned short* Sp = S + (long)lbh * T_ * T_;
        const int r0 = it * 256 + wr * 128 + ((lane >> 4) << 2);
        const int c0 = jt * 256 + wc * 64 + (lane & 15);
#pragma unroll
        for (int m = 0; m < 8; ++m) {
#pragma unroll
            for (int i = 0; i < 4; ++i) {
                const int rr = r0 + m * 16 + i;
#pragma unroll
                for (int n = 0; n < 4; ++n) {
                    const int cc = c0 + n * 16;
                    float v = (cc < rr) ? acc[m][n][i] : 0.0f;
                    Sp[(long)rr * T_ + cc] = f2bf(v);
                }
            }
        }
    } else {
        // raw f32 partial: part[pidx][256][256]
        float* Pp = part + (long)pidx * 65536;
        const int r0 = wr * 128 + ((lane >> 4) << 2);
        const int c0 = wc * 64 + (lane & 15);
#pragma unroll
        for (int m = 0; m < 8; ++m) {
#pragma unroll
            for (int i = 0; i < 4; ++i) {
                const int rr = r0 + m * 16 + i;
#pragma unroll
                for (int n = 0; n < 4; ++n)
                    Pp[rr * 256 + c0 + n * 16] = acc[m][n][i];
            }
        }
    }
#undef G256_STAGE
}

// ---------------------------------------------------------------------------
// reduce: sum 8 K-chunk partials, strict-lower mask, cast, store to S.
// grid: 32 tile-groups x 64 blocks; tile-group q -> lbh=q>>2, t36=32+(q&3)
// (it=7, jt=4+(q&3)).
// ---------------------------------------------------------------------------
__global__ __launch_bounds__(256) void reduce_kernel(
    const float* __restrict__ part, unsigned short* __restrict__ S)
{
    const int b = blockIdx.x;
    const int q = b >> 6;                     // 0..31
    const int e0 = (b & 63) * 1024 + threadIdx.x * 4;
    const int lbh = q >> 2;
    const int jt = 4 + (q & 3);
    const int it = 7;

    float4 s = {0.f, 0.f, 0.f, 0.f};
#pragma unroll
    for (int kc = 0; kc < 8; ++kc) {
        float4 p = *(const float4*)(part + ((long)(q * 8 + kc)) * 65536 + e0);
        s.x += p.x; s.y += p.y; s.z += p.z; s.w += p.w;
    }
    const int row = e0 >> 8;
    const int col = e0 & 255;
    const int rr = it * 256 + row;
    const int c0 = jt * 256 + col;
    unsigned short o[4];
#pragma unroll
    for (int k = 0; k < 4; ++k) {
        float v = ((c0 + k) < rr) ? ((const float*)&s)[k] : 0.0f;
        o[k] = f2bf(v);
    }
    unsigned short* Sp = S + (long)lbh * T_ * T_ + (long)rr * T_ + c0;
    Sp[0] = o[0]; Sp[1] = o[1]; Sp[2] = o[2]; Sp[3] = o[3];
}

// ---------------------------------------------------------------------------
// gemm2 (m97 structure, 128x128): O = S . V
// ---------------------------------------------------------------------------
__device__ __forceinline__ void stage_tile(const unsigned short* g, long ldk,
                                           unsigned short* l, int tid)
{
    const int row = tid >> 2;
    const int col = (tid & 3) << 3;
    const unsigned short* g0 = g + (long)row * ldk + col;
    const unsigned short* g1 = g0 + 64 * ldk;
    unsigned short* l0 = l + tid * 8;
    unsigned short* l1 = l0 + 2048;
    GLD16(g0, l0);
    GLD16(g1, l1);
}

__global__ __launch_bounds__(256) void gemm2_kernel(
    const unsigned short* __restrict__ S, const unsigned short* __restrict__ Vt,
    float* __restrict__ Out, int bh0)
{
    const int jn = blockIdx.x;
    const int it = blockIdx.y;
    const int lbh = blockIdx.z;
    const int bh = bh0 + lbh;
    const int b = bh / H_;

    __shared__ __align__(16) unsigned short As2[2][128][32];
    __shared__ __align__(16) unsigned short Bs2[2][128][32];

    const unsigned short* A  = S + (long)lbh * T_ * T_ + (long)it * 128 * T_;
    const unsigned short* Bm = Vt + (long)b * D_ * T_ + (long)jn * 128 * T_;
    const int KT = (it + 1) * 4;

    const int tid = threadIdx.x;
    const int lane = tid & 63;
    const int wid = tid >> 6;
    const int wr = wid >> 1;
    const int wc = wid & 1;
    f32x4 acc[4][4];
#pragma unroll
    for (int m = 0; m < 4; ++m)
#pragma unroll
        for (int n = 0; n < 4; ++n)
            acc[m][n] = (f32x4){0.f, 0.f, 0.f, 0.f};
    const int rofs = lane & 15;
    const int kofs = (lane >> 4) * 8;
    stage_tile(A, T_, &As2[0][0][0], tid);
    stage_tile(Bm, T_, &Bs2[0][0][0], tid);
    int cur = 0;
    for (int kt = 0; kt < KT; ++kt) {
        __syncthreads();
        if (kt + 1 < KT) {
            stage_tile(A + (long)(kt + 1) * 32, T_, &As2[cur ^ 1][0][0], tid);
            stage_tile(Bm + (long)(kt + 1) * 32, T_, &Bs2[cur ^ 1][0][0], tid);
        }
        bf16x8 af[4], bfr[4];
#pragma unroll
        for (int m = 0; m < 4; ++m)
            af[m] = *(const bf16x8*)&As2[cur][wr * 64 + m * 16 + rofs][kofs];
#pragma unroll
        for (int n = 0; n < 4; ++n)
            bfr[n] = *(const bf16x8*)&Bs2[cur][wc * 64 + n * 16 + rofs][kofs];
#pragma unroll
        for (int m = 0; m < 4; ++m)
#pragma unroll
            for (int n = 0; n < 4; ++n)
                acc[m][n] = __builtin_amdgcn_mfma_f32_16x16x32_bf16(
                    af[m], bfr[n], acc[m][n], 0, 0, 0);
        cur ^= 1;
    }

    float* Op = Out + ((long)bh * T_ + it * 128) * D_ + jn * 128;
#pragma unroll
    for (int m = 0; m < 4; ++m) {
        const int rbase = wr * 64 + m * 16 + ((lane >> 4) << 2);
#pragma unroll
        for (int i = 0; i < 4; ++i) {
            const int rr = rbase + i;
#pragma unroll
            for (int n = 0; n < 4; ++n) {
                const int cc = wc * 64 + n * 16 + (lane & 15);
                Op[(long)rr * D_ + cc] = acc[m][n][i];
            }
        }
    }
}

// ---------------------------------------------------------------------------
extern "C" void kernel_launch(void* const* d_in, const int* in_sizes, int n_in,
                              void* d_out, int out_size, void* d_ws, size_t ws_size,
                              hipStream_t stream)
{
    const float* Q = (const float*)d_in[0];
    const float* K = (const float*)d_in[1];
    const float* V = (const float*)d_in[2];
    float* Out = (float*)d_out;

    const size_t vt_elems = (size_t)B_ * D_ * T_;                 // bf16
    const size_t part_bytes = 256ull * 65536ull * 4ull;           // 67 MB
    auto need = [&](int c, bool split) {
        return 2 * vt_elems + (size_t)c * T_ * NH_ * 2 * 2        // Qb+Kb bytes
             + (size_t)c * T_ * T_ * 2                            // S bytes
             + (split ? part_bytes : 0);
    };
    int c; bool split;
    if      (ws_size >= need(8, true))  { c = 8; split = true; }
    else if (ws_size >= need(8, false)) { c = 8; split = false; }
    else if (ws_size >= need(4, false)) { c = 4; split = false; }
    else if (ws_size >= need(2, false)) { c = 2; split = false; }
    else if (ws_size >= need(1, false)) { c = 1; split = false; }
    else return;

    unsigned short* Vt = (unsigned short*)d_ws;
    unsigned short* Qb = Vt + vt_elems;
    unsigned short* Kb = Qb + (size_t)c * T_ * NH_;
    unsigned short* Sb = Kb + (size_t)c * T_ * NH_;
    float* part = (float*)(Sb + (size_t)c * T_ * T_);

    vcast_kernel<<<dim3(T_ / 64, D_ / 64, B_), 256, 0, stream>>>(V, Vt);

    for (int bh0 = 0; bh0 < B_ * H_; bh0 += c) {
        const long groups = (long)c * T_ * (NH_ / 8);
        rope_cast_kernel<<<(int)(groups / 256), 256, 0, stream>>>(Q, K, Qb, Kb, bh0);
        if (split) {
            gemm1_kernel<<<dim3(512), 512, 0, stream>>>(Qb, Kb, Sb, part, 1);
            reduce_kernel<<<dim3(32 * 64), 256, 0, stream>>>(part, Sb);
        } else {
            gemm1_kernel<<<dim3(36 * c), 512, 0, stream>>>(Qb, Kb, Sb, part, 0);
        }
        gemm2_kernel<<<dim3(2, 16, c), 256, 0, stream>>>(Sb, Vt, Out, bh0);
    }
}

// Round 11
// 661.594 us; speedup vs baseline: 7.2605x; 1.0093x over previous
//
#include <hip/hip_runtime.h>
#include <hip/hip_bf16.h>

#define B_ 2
#define H_ 4
#define T_ 2048
#define NH_ 8192
#define D_ 256

typedef __attribute__((ext_vector_type(4))) float f32x4;
typedef __attribute__((ext_vector_type(8))) short bf16x8;
typedef __attribute__((ext_vector_type(4))) int i32x4;

__device__ __forceinline__ unsigned short f2bf(float f) {
    union { float f; unsigned u; } v;
    v.f = f;
    unsigned u = v.u;
    unsigned r = u + 0x7FFFu + ((u >> 16) & 1u);   // RNE
    return (unsigned short)(r >> 16);
}

// ---------------------------------------------------------------------------
// Kernel 1: RoPE + cast to bf16 for Q and K (HBM-bound).
// ---------------------------------------------------------------------------
__global__ __launch_bounds__(256) void rope_cast_kernel(
    const float* __restrict__ Q, const float* __restrict__ K,
    unsigned short* __restrict__ Qb, unsigned short* __restrict__ Kb,
    int bh0)
{
    const long gid = (long)blockIdx.x * 256 + threadIdx.x;  // one 8-elem group
    const int ng = NH_ / 8;
    const int n8 = (int)(gid % ng) * 8;
    const long row = gid / ng;              // lbh*T + t
    const int t = (int)(row % T_);
    const int lbh = (int)(row / T_);

    const long in_off  = ((long)(bh0 + lbh) * T_ + t) * NH_ + n8;
    const long out_off = ((long)lbh * T_ + t) * NH_ + n8;

    float4 qa = *(const float4*)(Q + in_off);
    float4 qb4 = *(const float4*)(Q + in_off + 4);
    float4 ka = *(const float4*)(K + in_off);
    float4 kb4 = *(const float4*)(K + in_off + 4);
    float qv[8] = {qa.x, qa.y, qa.z, qa.w, qb4.x, qb4.y, qb4.z, qb4.w};
    float kv[8] = {ka.x, ka.y, ka.z, ka.w, kb4.x, kb4.y, kb4.z, kb4.w};

    union { i32x4 v; unsigned short u[8]; } qo, ko;
    const int p0 = n8 >> 1;
    const float tf = (float)t;
#pragma unroll
    for (int j = 0; j < 4; ++j) {
        float freq = exp2f(-(float)(p0 + j) * (1.0f / 256.0f)) * 0.15915494309189535f;
        float phase = tf * freq;
        float r = phase - floorf(phase);        // revolutions in [0,1)
        float c, s;
        asm("v_cos_f32 %0, %1" : "=v"(c) : "v"(r));
        asm("v_sin_f32 %0, %1" : "=v"(s) : "v"(r));
        float qe = qv[2 * j], qodd = qv[2 * j + 1];
        float ke = kv[2 * j], kodd = kv[2 * j + 1];
        qo.u[2 * j]     = f2bf(qe * c - qodd * s);
        qo.u[2 * j + 1] = f2bf(qodd * c + qe * s);
        ko.u[2 * j]     = f2bf(ke * c - kodd * s);
        ko.u[2 * j + 1] = f2bf(kodd * c + ke * s);
    }
    *(i32x4*)(Qb + out_off) = qo.v;
    *(i32x4*)(Kb + out_off) = ko.v;
}

// ---------------------------------------------------------------------------
// Kernel 2: V [B,T,D] fp32 -> Vt [B,D,T] bf16 (transposed cast, LDS tiled)
// ---------------------------------------------------------------------------
__global__ __launch_bounds__(256) void vcast_kernel(
    const float* __restrict__ V, unsigned short* __restrict__ Vt)
{
    __shared__ unsigned short tile[64][72];
    const int t0 = blockIdx.x * 64;
    const int d0 = blockIdx.y * 64;
    const int b = blockIdx.z;
    const int tid = threadIdx.x;
#pragma unroll
    for (int rr = 0; rr < 16; ++rr) {
        int tl = rr * 4 + (tid >> 6);
        int dl = tid & 63;
        float v = V[((long)b * T_ + (t0 + tl)) * D_ + d0 + dl];
        tile[dl][tl] = f2bf(v);
    }
    __syncthreads();
#pragma unroll
    for (int rr = 0; rr < 16; ++rr) {
        int dl = rr * 4 + (tid >> 6);
        int tl = tid & 63;
        Vt[((long)b * D_ + (d0 + dl)) * T_ + t0 + tl] = tile[dl][tl];
    }
}

// ---------------------------------------------------------------------------
// gemm1: S = mask(Qr . Kr^T).  256x256, 512 thr / 8 waves.  REG-STAGING
// transport (this round's single change): R4-R10 all pinned at ~80 cyc per
// global_load_lds instruction per CU (~30 GB/s/CU, L2-miss DMA serialization);
// reg-staging (global_load_dwordx4 -> VGPR ping-pong -> ds_write_b128)
// sidesteps the LDS-DMA path (HK's approach, ~58 GB/s/CU).  Same global
// source addresses (pre-swizzled) and same linear LDS dest; double-buffered
// 64 KiB LDS; ONE raw barrier + lgkmcnt(0) per K-step (NOT __syncthreads --
// that drains vmcnt(0) and kills the pipeline).  Compiler inserts counted
// vmcnt(4) before each ds_write automatically.  Buffer parity: tile t lives
// in buf[t&1]; X regs carry even tiles, Y odd (static names, rule #20).
// Schedule/decode/epilogue identical to R10 (validated).
// ---------------------------------------------------------------------------
#define GLD16(g, l) __builtin_amdgcn_global_load_lds(                         \
    (const __attribute__((address_space(1))) void*)(g),                       \
    (__attribute__((address_space(3))) void*)(l), 16, 0, 0)

__global__ __launch_bounds__(512, 2) void gemm1_kernel(
    const unsigned short* __restrict__ Qb, const unsigned short* __restrict__ Kb,
    unsigned short* __restrict__ S, float* __restrict__ part, int split)
{
    __shared__ __align__(16) unsigned short As[2][256][32];   // 32 KiB
    __shared__ __align__(16) unsigned short Bs[2][256][32];   // 32 KiB

    const int bidx = blockIdx.x;
    int lbh, t36, KT, kc, pidx;
    bool full;
    if (split) {
        lbh = bidx & 7;
        const int s = bidx >> 3;             // 0..63
        if (s < 32) { t36 = s; KT = 256; kc = 0; full = true; pidx = 0; }
        else {
            const int j = s - 32;            // 0..31
            t36 = 32 + (j >> 3);             // 32..35
            kc = j & 7;
            KT = 32; full = false;
            pidx = (lbh * 4 + (t36 - 32)) * 8 + kc;
        }
    } else {
        lbh = bidx / 36; t36 = bidx % 36; KT = 256; kc = 0; full = true; pidx = 0;
    }
    int it = (int)((sqrtf(8.0f * (float)t36 + 1.0f) - 1.0f) * 0.5f);
    if ((it + 1) * (it + 2) / 2 <= t36) ++it;
    if (it * (it + 1) / 2 > t36) --it;
    const int jt = t36 - it * (it + 1) / 2;

    const int tid = threadIdx.x;
    const int lane = tid & 63;
    const int wid = tid >> 6;                // 0..7
    const int wr = wid >> 2;                 // 0..1 (128-row half)
    const int wc = wid & 3;                  // 0..3 (64-col quarter)
    const int rofs = lane & 15;
    const int sl8 = (((lane >> 4) ^ ((lane >> 1) & 3))) << 3;  // read swizzle

    const int ss8 = (((tid & 3) ^ ((tid >> 3) & 3))) << 3;     // src pre-swizzle
    const int dst = tid * 8;                 // elems within one [128][32] half
    const long K0 = (long)kc * 1024;
    const unsigned short* Ab = Qb + (long)lbh * T_ * NH_ + (long)it * 256 * NH_ + K0;
    const unsigned short* Bb = Kb + (long)lbh * T_ * NH_ + (long)jt * 256 * NH_ + K0;
    const unsigned short* gA0 = Ab + (long)(tid >> 2) * NH_ + ss8;
    const unsigned short* gA1 = gA0 + 128L * NH_;
    const unsigned short* gB0 = Bb + (long)(tid >> 2) * NH_ + ss8;
    const unsigned short* gB1 = gB0 + 128L * NH_;
    unsigned short* AsB = &As[0][0][0];
    unsigned short* BsB = &Bs[0][0][0];

    f32x4 acc[8][4];
#pragma unroll
    for (int m = 0; m < 8; ++m)
#pragma unroll
        for (int n = 0; n < 4; ++n)
            acc[m][n] = (f32x4){0.f, 0.f, 0.f, 0.f};

    i32x4 xa0, xa1, xb0, xb1;    // even-tile staging regs
    i32x4 ya0, ya1, yb0, yb1;    // odd-tile staging regs

#define LDX(kt) { const long ko_ = (long)(kt) * 32;                           \
    xa0 = *(const i32x4*)(gA0 + ko_); xa1 = *(const i32x4*)(gA1 + ko_);       \
    xb0 = *(const i32x4*)(gB0 + ko_); xb1 = *(const i32x4*)(gB1 + ko_); }
#define LDY(kt) { const long ko_ = (long)(kt) * 32;                           \
    ya0 = *(const i32x4*)(gA0 + ko_); ya1 = *(const i32x4*)(gA1 + ko_);       \
    yb0 = *(const i32x4*)(gB0 + ko_); yb1 = *(const i32x4*)(gB1 + ko_); }
#define WRX(P) {                                                              \
    *(i32x4*)(AsB + (P) * 8192 + dst) = xa0;                                  \
    *(i32x4*)(AsB + (P) * 8192 + 4096 + dst) = xa1;                           \
    *(i32x4*)(BsB + (P) * 8192 + dst) = xb0;                                  \
    *(i32x4*)(BsB + (P) * 8192 + 4096 + dst) = xb1; }
#define WRY(P) {                                                              \
    *(i32x4*)(AsB + (P) * 8192 + dst) = ya0;                                  \
    *(i32x4*)(AsB + (P) * 8192 + 4096 + dst) = ya1;                           \
    *(i32x4*)(BsB + (P) * 8192 + dst) = yb0;                                  \
    *(i32x4*)(BsB + (P) * 8192 + 4096 + dst) = yb1; }
#define BARR { asm volatile("s_waitcnt lgkmcnt(0)" ::: "memory");             \
    __builtin_amdgcn_s_barrier();                                             \
    __builtin_amdgcn_sched_barrier(0); }
#define MM(P) { bf16x8 af[8], bv[4];                                          \
    const unsigned short* ab = AsB + (P) * 8192 + sl8;                        \
    const unsigned short* bb = BsB + (P) * 8192 + sl8;                        \
    _Pragma("unroll") for (int n = 0; n < 4; ++n)                             \
        bv[n] = *(const bf16x8*)(bb + (brow + n * 16) * 32);                  \
    _Pragma("unroll") for (int m = 0; m < 8; ++m)                             \
        af[m] = *(const bf16x8*)(ab + (arow + m * 16) * 32);                  \
    __builtin_amdgcn_s_setprio(1);                                            \
    _Pragma("unroll") for (int m = 0; m < 8; ++m)                             \
        _Pragma("unroll") for (int n = 0; n < 4; ++n)                         \
            acc[m][n] = __builtin_amdgcn_mfma_f32_16x16x32_bf16(              \
                af[m], bv[n], acc[m][n], 0, 0, 0);                            \
    __builtin_amdgcn_s_setprio(0); }

    const int arow = wr * 128 + rofs;
    const int brow = wc * 64 + rofs;

    // prologue: tiles 0,1 loading; write tile0 (compiler waits vmcnt(4))
    LDX(0)
    LDY(1)
    WRX(0)
    BARR

#pragma unroll 1
    for (int t = 0; t + 2 < KT; t += 2) {
        LDX(t + 2)
        MM(0)
        WRY(1)                     // tile t+1 -> buf1 (auto vmcnt(4))
        BARR
        if (t + 3 < KT) LDY(t + 3)
        MM(1)
        WRX(0)                     // tile t+2 -> buf0
        BARR
    }
    MM(0)                          // tile KT-2
    WRY(1)                         // tile KT-1 (auto vmcnt(0))
    BARR
    MM(1)                          // tile KT-1

    if (full) {
        unsigned short* Sp = S + (long)lbh * T_ * T_;
        const int r0 = it * 256 + wr * 128 + ((lane >> 4) << 2);
        const int c0 = jt * 256 + wc * 64 + (lane & 15);
#pragma unroll
        for (int m = 0; m < 8; ++m) {
#pragma unroll
            for (int i = 0; i < 4; ++i) {
                const int rr = r0 + m * 16 + i;
#pragma unroll
                for (int n = 0; n < 4; ++n) {
                    const int cc = c0 + n * 16;
                    float v = (cc < rr) ? acc[m][n][i] : 0.0f;
                    Sp[(long)rr * T_ + cc] = f2bf(v);
                }
            }
        }
    } else {
        float* Pp = part + (long)pidx * 65536;
        const int r0 = wr * 128 + ((lane >> 4) << 2);
        const int c0 = wc * 64 + (lane & 15);
#pragma unroll
        for (int m = 0; m < 8; ++m) {
#pragma unroll
            for (int i = 0; i < 4; ++i) {
                const int rr = r0 + m * 16 + i;
#pragma unroll
                for (int n = 0; n < 4; ++n)
                    Pp[rr * 256 + c0 + n * 16] = acc[m][n][i];
            }
        }
    }
#undef LDX
#undef LDY
#undef WRX
#undef WRY
#undef BARR
#undef MM
}

// ---------------------------------------------------------------------------
// reduce: sum 8 K-chunk partials, strict-lower mask, cast, store to S.
// ---------------------------------------------------------------------------
__global__ __launch_bounds__(256) void reduce_kernel(
    const float* __restrict__ part, unsigned short* __restrict__ S)
{
    const int b = blockIdx.x;
    const int q = b >> 6;                     // 0..31
    const int e0 = (b & 63) * 1024 + threadIdx.x * 4;
    const int lbh = q >> 2;
    const int jt = 4 + (q & 3);
    const int it = 7;

    float4 s = {0.f, 0.f, 0.f, 0.f};
#pragma unroll
    for (int kc = 0; kc < 8; ++kc) {
        float4 p = *(const float4*)(part + ((long)(q * 8 + kc)) * 65536 + e0);
        s.x += p.x; s.y += p.y; s.z += p.z; s.w += p.w;
    }
    const int row = e0 >> 8;
    const int col = e0 & 255;
    const int rr = it * 256 + row;
    const int c0 = jt * 256 + col;
    unsigned short o[4];
#pragma unroll
    for (int k = 0; k < 4; ++k) {
        float v = ((c0 + k) < rr) ? ((const float*)&s)[k] : 0.0f;
        o[k] = f2bf(v);
    }
    unsigned short* Sp = S + (long)lbh * T_ * T_ + (long)rr * T_ + c0;
    Sp[0] = o[0]; Sp[1] = o[1]; Sp[2] = o[2]; Sp[3] = o[3];
}

// ---------------------------------------------------------------------------
// gemm2 (m97 structure, 128x128): O = S . V
// ---------------------------------------------------------------------------
__device__ __forceinline__ void stage_tile(const unsigned short* g, long ldk,
                                           unsigned short* l, int tid)
{
    const int row = tid >> 2;
    const int col = (tid & 3) << 3;
    const unsigned short* g0 = g + (long)row * ldk + col;
    const unsigned short* g1 = g0 + 64 * ldk;
    unsigned short* l0 = l + tid * 8;
    unsigned short* l1 = l0 + 2048;
    GLD16(g0, l0);
    GLD16(g1, l1);
}

__global__ __launch_bounds__(256) void gemm2_kernel(
    const unsigned short* __restrict__ S, const unsigned short* __restrict__ Vt,
    float* __restrict__ Out, int bh0)
{
    const int jn = blockIdx.x;
    const int it = blockIdx.y;
    const int lbh = blockIdx.z;
    const int bh = bh0 + lbh;
    const int b = bh / H_;

    __shared__ __align__(16) unsigned short As2[2][128][32];
    __shared__ __align__(16) unsigned short Bs2[2][128][32];

    const unsigned short* A  = S + (long)lbh * T_ * T_ + (long)it * 128 * T_;
    const unsigned short* Bm = Vt + (long)b * D_ * T_ + (long)jn * 128 * T_;
    const int KT = (it + 1) * 4;

    const int tid = threadIdx.x;
    const int lane = tid & 63;
    const int wid = tid >> 6;
    const int wr = wid >> 1;
    const int wc = wid & 1;
    f32x4 acc[4][4];
#pragma unroll
    for (int m = 0; m < 4; ++m)
#pragma unroll
        for (int n = 0; n < 4; ++n)
            acc[m][n] = (f32x4){0.f, 0.f, 0.f, 0.f};
    const int rofs = lane & 15;
    const int kofs = (lane >> 4) * 8;
    stage_tile(A, T_, &As2[0][0][0], tid);
    stage_tile(Bm, T_, &Bs2[0][0][0], tid);
    int cur = 0;
    for (int kt = 0; kt < KT; ++kt) {
        __syncthreads();
        if (kt + 1 < KT) {
            stage_tile(A + (long)(kt + 1) * 32, T_, &As2[cur ^ 1][0][0], tid);
            stage_tile(Bm + (long)(kt + 1) * 32, T_, &Bs2[cur ^ 1][0][0], tid);
        }
        bf16x8 af[4], bfr[4];
#pragma unroll
        for (int m = 0; m < 4; ++m)
            af[m] = *(const bf16x8*)&As2[cur][wr * 64 + m * 16 + rofs][kofs];
#pragma unroll
        for (int n = 0; n < 4; ++n)
            bfr[n] = *(const bf16x8*)&Bs2[cur][wc * 64 + n * 16 + rofs][kofs];
#pragma unroll
        for (int m = 0; m < 4; ++m)
#pragma unroll
            for (int n = 0; n < 4; ++n)
                acc[m][n] = __builtin_amdgcn_mfma_f32_16x16x32_bf16(
                    af[m], bfr[n], acc[m][n], 0, 0, 0);
        cur ^= 1;
    }

    float* Op = Out + ((long)bh * T_ + it * 128) * D_ + jn * 128;
#pragma unroll
    for (int m = 0; m < 4; ++m) {
        const int rbase = wr * 64 + m * 16 + ((lane >> 4) << 2);
#pragma unroll
        for (int i = 0; i < 4; ++i) {
            const int rr = rbase + i;
#pragma unroll
            for (int n = 0; n < 4; ++n) {
                const int cc = wc * 64 + n * 16 + (lane & 15);
                Op[(long)rr * D_ + cc] = acc[m][n][i];
            }
        }
    }
}

// ---------------------------------------------------------------------------
extern "C" void kernel_launch(void* const* d_in, const int* in_sizes, int n_in,
                              void* d_out, int out_size, void* d_ws, size_t ws_size,
                              hipStream_t stream)
{
    const float* Q = (const float*)d_in[0];
    const float* K = (const float*)d_in[1];
    const float* V = (const float*)d_in[2];
    float* Out = (float*)d_out;

    const size_t vt_elems = (size_t)B_ * D_ * T_;                 // bf16
    const size_t part_bytes = 256ull * 65536ull * 4ull;           // 67 MB
    auto need = [&](int c, bool split) {
        return 2 * vt_elems + (size_t)c * T_ * NH_ * 2 * 2        // Qb+Kb bytes
             + (size_t)c * T_ * T_ * 2                            // S bytes
             + (split ? part_bytes : 0);
    };
    int c; bool split;
    if      (ws_size >= need(8, true))  { c = 8; split = true; }
    else if (ws_size >= need(8, false)) { c = 8; split = false; }
    else if (ws_size >= need(4, false)) { c = 4; split = false; }
    else if (ws_size >= need(2, false)) { c = 2; split = false; }
    else if (ws_size >= need(1, false)) { c = 1; split = false; }
    else return;

    unsigned short* Vt = (unsigned short*)d_ws;
    unsigned short* Qb = Vt + vt_elems;
    unsigned short* Kb = Qb + (size_t)c * T_ * NH_;
    unsigned short* Sb = Kb + (size_t)c * T_ * NH_;
    float* part = (float*)(Sb + (size_t)c * T_ * T_);

    vcast_kernel<<<dim3(T_ / 64, D_ / 64, B_), 256, 0, stream>>>(V, Vt);

    for (int bh0 = 0; bh0 < B_ * H_; bh0 += c) {
        const long groups = (long)c * T_ * (NH_ / 8);
        rope_cast_kernel<<<(int)(groups / 256), 256, 0, stream>>>(Q, K, Qb, Kb, bh0);
        if (split) {
            gemm1_kernel<<<dim3(512), 512, 0, stream>>>(Qb, Kb, Sb, part, 1);
            reduce_kernel<<<dim3(32 * 64), 256, 0, stream>>>(part, Sb);
        } else {
            gemm1_kernel<<<dim3(36 * c), 512, 0, stream>>>(Qb, Kb, Sb, part, 0);
        }
        gemm2_kernel<<<dim3(2, 16, c), 256, 0, stream>>>(Sb, Vt, Out, bh0);
    }
}